// Round 1
// baseline (71.919 us; speedup 1.0000x reference)
//
#include <hip/hip_runtime.h>
#include <math.h>

// Problem constants (fixed by setup_inputs).
#define CC 4
#define NN 4096                  // vertices per class (== queries per class)
#define MM 4096
#define DD 32
#define GR 10                    // grid resolution per axis
#define NCELL (GR * GR * GR)     // 1000 cells per class
#define LPQ 16                   // lanes cooperating per query
#define BBLK 1024                // build threads per block
#define QBLK 256                 // query threads per block
#define QPB (QBLK / LPQ)         // 16 queries per block

// Workspace layout (needs 272.4 KB; ws is ~268 MB):
//   float4 pts[CC][NN]     @ 0        : cell-sorted {x,y,z,bitcast(local idx)}
//   uint   starts[CC][1024]@ 256 KB   : 1001 exclusive cell starts per class
#define STARTS_OFF ((size_t)CC * NN * 16)
#define START_STRIDE 1024

__device__ __forceinline__ int cellof(float x) {
    int c = (int)(x * (float)GR);
    return min(max(c, 0), GR - 1);
}

// Branchless sorted-insert of (d, j) into top-3 (d0<=d1<=d2). Strict <
// keeps earlier entries on ties (matches jax top_k tie-break).
__device__ __forceinline__ void ins3b(float d, int j,
                                      float& d0, float& d1, float& d2,
                                      int& i0, int& i1, int& i2) {
    bool l2 = d < d2, l1 = d < d1, l0 = d < d0;
    d2 = l1 ? d1 : (l2 ? d : d2);
    i2 = l1 ? i1 : (l2 ? j : i2);
    d1 = l0 ? d0 : (l1 ? d : d1);
    i1 = l0 ? i0 : (l1 ? j : i1);
    d0 = l0 ? d : d0;
    i0 = l0 ? j : i0;
}

// ---- Kernel 1: build the cell-sorted index ONCE per class (4 blocks). ----
// Same count/scan/scatter as the previous single-kernel version, but emits
// the sorted SoA to global workspace so 1024 query blocks don't replicate it.
__global__ __launch_bounds__(BBLK) void k_build(
    const float* __restrict__ verts,      // [CC,NN,3]
    float4* __restrict__ wsP,             // [CC,NN] sorted points
    unsigned* __restrict__ wsS)           // [CC,1024] cell starts
{
    __shared__ unsigned cnt[NCELL];       // counts -> scatter cursor
    __shared__ unsigned wsum[BBLK / 64];

    const int tid = threadIdx.x;
    const int c   = blockIdx.x;

    if (tid < NCELL) cnt[tid] = 0u;
    const float4* src4 = (const float4*)(verts + (size_t)c * NN * 3);
    const float4 fa = src4[3 * tid];
    const float4 fb = src4[3 * tid + 1];
    const float4 fc = src4[3 * tid + 2];
    const float px[4] = {fa.x, fa.w, fb.z, fc.y};
    const float py[4] = {fa.y, fb.x, fb.w, fc.z};
    const float pz[4] = {fa.z, fb.y, fc.x, fc.w};
    __syncthreads();                      // cnt zeroed

    int cell[4];
    #pragma unroll
    for (int u = 0; u < 4; ++u) {
        cell[u] = (cellof(px[u]) * GR + cellof(py[u])) * GR + cellof(pz[u]);
        atomicAdd(&cnt[cell[u]], 1u);
    }
    __syncthreads();

    // Exclusive scan of 1000 counts (thread t owns cell t).
    const int lane = tid & 63, wid = tid >> 6;
    const unsigned own = (tid < NCELL) ? cnt[tid] : 0u;
    unsigned incl = own;
    #pragma unroll
    for (int off = 1; off < 64; off <<= 1) {
        unsigned v = __shfl_up(incl, off);
        if (lane >= off) incl += v;
    }
    if (lane == 63) wsum[wid] = incl;
    __syncthreads();
    unsigned wbase = 0;
    for (int w = 0; w < wid; ++w) wbase += wsum[w];
    unsigned* Sc = wsS + (size_t)c * START_STRIDE;
    if (tid < NCELL) {
        const unsigned excl = wbase + incl - own;
        cnt[tid] = excl;                  // scatter cursor
        Sc[tid]  = excl;                  // global starts table
    }
    if (tid == BBLK - 1) Sc[NCELL] = wbase + incl;   // == NN
    __syncthreads();

    // Scatter into cell-sorted float4 {x,y,z,idx} in global (L2-resident).
    float4* Pc = wsP + (size_t)c * NN;
    #pragma unroll
    for (int u = 0; u < 4; ++u) {
        const unsigned pos = atomicAdd(&cnt[cell[u]], 1u);
        Pc[pos] = make_float4(px[u], py[u], pz[u],
                              __int_as_float(4 * tid + u));
    }
}

// ---- Kernel 2: answer queries from the L2-resident sorted index. ----
// 16 queries/block, 16 lanes/query, one barrier (starts staging), no build.
__global__ __launch_bounds__(QBLK) void k_query(
    const float2* __restrict__ feat2,     // [CC*NN][16] float2
    const float* __restrict__ nverts,     // [CC,MM,3]
    const float4* __restrict__ wsP,
    const unsigned* __restrict__ wsS,
    float2* __restrict__ out2)            // [CC*MM][16] float2
{
    __shared__ unsigned sstart[NCELL + 1];   // 4 KB starts copy

    const int tid = threadIdx.x;
    const int g   = tid >> 4;                // group 0..15
    const int t   = tid & (LPQ - 1);
    const int m   = blockIdx.x * QPB + g;    // global query slot
    const int c   = (blockIdx.x * QPB) >> 12;   // block-uniform class

    // Stage the class's 1001 starts into LDS (coalesced, L2 broadcast).
    const unsigned* Sc = wsS + (size_t)c * START_STRIDE;
    for (int i = tid; i <= NCELL; i += QBLK) sstart[i] = Sc[i];

    const float qx = nverts[3 * m + 0];
    const float qy = nverts[3 * m + 1];
    const float qz = nverts[3 * m + 2];
    __syncthreads();

    const float4* Pc = wsP + (size_t)c * NN;

    const int cx = cellof(qx), cy = cellof(qy), cz = cellof(qz);
    const int offb = (c == 0) ? NN : (-c * NN);   // off-block 1.0 seed indices
    const float cs = 1.0f / (float)GR;

    float d0 = 1.0f, d1 = 1.0f, d2 = 1.0f;
    int   i0 = offb, i1 = offb + 1, i2 = offb + 2;

    const int lz = max(cz - 1, 0), hz = min(cz + 1, GR - 1);

    // 9 z-column ranges from LDS starts (broadcast within group).
    unsigned aa[9], bb[9];
    #pragma unroll
    for (int j = 0; j < 9; ++j) {
        const int ppx = cx + j / 3 - 1, ppy = cy + j % 3 - 1;
        const bool ok = (ppx >= 0) & (ppx < GR) & (ppy >= 0) & (ppy < GR);
        const int rb = ok ? ((ppx * GR + ppy) * GR) : 0;
        const unsigned av = sstart[rb + lz];
        const unsigned bv = sstart[rb + hz + 1];
        aa[j] = av;
        bb[j] = ok ? bv : av;                // empty if out of grid
    }

    // 2-deep predicated batch: lanes t and t+16 cover 32 pts/column.
    // Points come as one global_load_dwordx4 each (L2-resident, 768 KB).
    unsigned over = 0u;
    #pragma unroll
    for (int j = 0; j < 9; ++j) {
        const unsigned s0 = aa[j] + t, s1 = s0 + LPQ;
        const unsigned u0 = (s0 < bb[j]) ? s0 : 0u;
        const unsigned u1 = (s1 < bb[j]) ? s1 : 0u;
        const float4 p0 = Pc[u0];
        const float4 p1 = Pc[u1];
        float dx = p0.x - qx, dy = p0.y - qy, dz = p0.z - qz;
        float dd = fmaf(dx, dx, fmaf(dy, dy, dz * dz));
        dd = (s0 < bb[j]) ? dd : 1e30f;
        ins3b(dd, __float_as_int(p0.w), d0, d1, d2, i0, i1, i2);
        dx = p1.x - qx; dy = p1.y - qy; dz = p1.z - qz;
        float de = fmaf(dx, dx, fmaf(dy, dy, dz * dz));
        de = (s1 < bb[j]) ? de : 1e30f;
        ins3b(de, __float_as_int(p1.w), d0, d1, d2, i0, i1, i2);
        over |= (bb[j] - aa[j] > 2u * LPQ) ? 1u : 0u;
    }
    if (over) {                              // rare: columns > 32 pts
        #pragma unroll 1
        for (int j = 0; j < 9; ++j) {
            for (unsigned s = aa[j] + 2u * LPQ + t; s < bb[j]; s += LPQ) {
                const float4 p = Pc[s];
                const float dx = p.x - qx, dy = p.y - qy, dz = p.z - qz;
                const float dd = fmaf(dx, dx, fmaf(dy, dy, dz * dz));
                ins3b(dd, __float_as_int(p.w), d0, d1, d2, i0, i1, i2);
            }
        }
    }

    // Merge sorted triples across the 16-lane group.
    #pragma unroll
    for (int mask = 1; mask < LPQ; mask <<= 1) {
        const float e0 = __shfl_xor(d0, mask);
        const float e1 = __shfl_xor(d1, mask);
        const float e2 = __shfl_xor(d2, mask);
        const int   j0 = __shfl_xor(i0, mask);
        const int   j1 = __shfl_xor(i1, mask);
        const int   j2 = __shfl_xor(i2, mask);
        ins3b(e0, j0, d0, d1, d2, i0, i1, i2);
        ins3b(e1, j1, d0, d1, d2, i0, i1, i2);
        ins3b(e2, j2, d0, d1, d2, i0, i1, i2);
    }

    // Certificate for r=1 (group-uniform); rare exact expanding rescan.
    {
        const int lx = max(cx - 1, 0), hx = min(cx + 1, GR - 1);
        const int ly = max(cy - 1, 0), hy = min(cy + 1, GR - 1);
        float rmin = 1e30f;
        if (lx > 0)      rmin = fminf(rmin, qx - (float)lx * cs);
        if (hx < GR - 1) rmin = fminf(rmin, (float)(hx + 1) * cs - qx);
        if (ly > 0)      rmin = fminf(rmin, qy - (float)ly * cs);
        if (hy < GR - 1) rmin = fminf(rmin, (float)(hy + 1) * cs - qy);
        if (lz > 0)      rmin = fminf(rmin, qz - (float)lz * cs);
        if (hz < GR - 1) rmin = fminf(rmin, (float)(hz + 1) * cs - qz);

        if (!(d2 <= rmin * rmin)) {          // P ~ 5.8e-6 per query
            for (int r = 2;; ++r) {
                d0 = d1 = d2 = 1.0f;
                i0 = offb; i1 = offb + 1; i2 = offb + 2;
                const int Lx = max(cx - r, 0), Hx = min(cx + r, GR - 1);
                const int Ly = max(cy - r, 0), Hy = min(cy + r, GR - 1);
                const int Lz = max(cz - r, 0), Hz = min(cz + r, GR - 1);
                for (int ppx = Lx; ppx <= Hx; ++ppx) {
                    for (int ppy = Ly; ppy <= Hy; ++ppy) {
                        const int rb = (ppx * GR + ppy) * GR;
                        const unsigned a = sstart[rb + Lz];
                        const unsigned b = sstart[rb + Hz + 1];
                        for (unsigned s = a + t; s < b; s += LPQ) {
                            const float4 p = Pc[s];
                            const float dx = p.x - qx, dy = p.y - qy,
                                        dz = p.z - qz;
                            const float dd =
                                fmaf(dx, dx, fmaf(dy, dy, dz * dz));
                            ins3b(dd, __float_as_int(p.w),
                                  d0, d1, d2, i0, i1, i2);
                        }
                    }
                }
                #pragma unroll
                for (int mask = 1; mask < LPQ; mask <<= 1) {
                    const float e0 = __shfl_xor(d0, mask);
                    const float e1 = __shfl_xor(d1, mask);
                    const float e2 = __shfl_xor(d2, mask);
                    const int   j0 = __shfl_xor(i0, mask);
                    const int   j1 = __shfl_xor(i1, mask);
                    const int   j2 = __shfl_xor(i2, mask);
                    ins3b(e0, j0, d0, d1, d2, i0, i1, i2);
                    ins3b(e1, j1, d0, d1, d2, i0, i1, i2);
                    ins3b(e2, j2, d0, d1, d2, i0, i1, i2);
                }
                float rm = 1e30f;
                if (Lx > 0)      rm = fminf(rm, qx - (float)Lx * cs);
                if (Hx < GR - 1) rm = fminf(rm, (float)(Hx + 1) * cs - qx);
                if (Ly > 0)      rm = fminf(rm, qy - (float)Ly * cs);
                if (Hy < GR - 1) rm = fminf(rm, (float)(Hy + 1) * cs - qy);
                if (Lz > 0)      rm = fminf(rm, qz - (float)Lz * cs);
                if (Hz < GR - 1) rm = fminf(rm, (float)(Hz + 1) * cs - qz);
                const bool full = (Lx == 0 && Ly == 0 && Lz == 0 &&
                                   Hx == GR - 1 && Hy == GR - 1 &&
                                   Hz == GR - 1);
                if (full || d2 <= rm * rm) break;
            }
        }
    }

    // Fused epilogue: softmax(-d) + weighted feature gather (float2/lane).
    float w1 = expf(d0 - d1);
    float w2 = expf(d0 - d2);
    const float inv = 1.0f / (1.0f + w1 + w2);
    const float w0 = inv;
    w1 *= inv; w2 *= inv;

    const float2 a  = feat2[(size_t)(i0 + c * NN) * 16 + t];
    const float2 b  = feat2[(size_t)(i1 + c * NN) * 16 + t];
    const float2 gg = feat2[(size_t)(i2 + c * NN) * 16 + t];
    float2 o;
    o.x = w0 * a.x + w1 * b.x + w2 * gg.x;
    o.y = w0 * a.y + w1 * b.y + w2 * gg.y;
    out2[(size_t)m * 16 + t] = o;            // natural order -> coalesced
}

extern "C" void kernel_launch(void* const* d_in, const int* in_sizes, int n_in,
                              void* d_out, int out_size, void* d_ws, size_t ws_size,
                              hipStream_t stream) {
    const float* feat   = (const float*)d_in[0];   // points_feat [1, C*N, D] f32
    const float* verts  = (const float*)d_in[1];   // vertices    [C, N, 3]  f32
    const float* nverts = (const float*)d_in[2];   // new_vertices[C, M, 3]  f32
    float* outp = (float*)d_out;                   // [1, C*M, D] f32

    float4*   wsP = (float4*)d_ws;
    unsigned* wsS = (unsigned*)((char*)d_ws + STARTS_OFF);

    k_build<<<dim3(CC), dim3(BBLK), 0, stream>>>(verts, wsP, wsS);
    k_query<<<dim3(CC * MM / QPB), dim3(QBLK), 0, stream>>>(
        (const float2*)feat, nverts, wsP, wsS, (float2*)outp);
}

// Round 2
// 67.530 us; speedup vs baseline: 1.0650x; 1.0650x over previous
//
#include <hip/hip_runtime.h>
#include <math.h>

// Problem constants (fixed by setup_inputs).
#define CC 4
#define NN 4096                  // vertices per class (== queries per class)
#define MM 4096
#define DD 32
#define GR 10                    // grid resolution per axis
#define NCELL (GR * GR * GR)     // 1000 cells per class
#define LPQ 16                   // lanes cooperating per query
#define BLK 512                  // threads per block (8 waves -> 2 blocks/CU)
#define QPB 32                   // queries per block
#define PPT 8                    // points staged per thread (NN/BLK)

__device__ __forceinline__ int cellof(float x) {
    int c = (int)(x * (float)GR);
    return min(max(c, 0), GR - 1);
}

// Branchless sorted-insert of (d, j) into top-3 (d0<=d1<=d2). Strict <
// keeps earlier entries on ties (matches jax top_k tie-break).
__device__ __forceinline__ void ins3b(float d, int j,
                                      float& d0, float& d1, float& d2,
                                      int& i0, int& i1, int& i2) {
    bool l2 = d < d2, l1 = d < d1, l0 = d < d0;
    d2 = l1 ? d1 : (l2 ? d : d2);
    i2 = l1 ? i1 : (l2 ? j : i2);
    d1 = l0 ? d0 : (l1 ? d : d1);
    i1 = l0 ? i0 : (l1 ? j : i1);
    d0 = l0 ? d : d0;
    i0 = l0 ? j : i0;
}

// ONE fused kernel. Each block privately builds the full cell index of its
// class in LDS (count -> scan -> scatter), then answers 32 queries with
// 16 lanes each. 512 blocks -> 2 blocks/CU so one block's barrier/latency
// stalls are hidden by the co-resident block's work.
__global__ __launch_bounds__(BLK, 4) void k_all(
    const float2* __restrict__ feat2,     // [CC*NN][16] float2
    const float* __restrict__ verts,      // [CC,NN,3]
    const float* __restrict__ nverts,     // [CC,MM,3]
    float2* __restrict__ out2)            // [CC*MM][16] float2
{
    __shared__ float sx[NN], sy[NN], sz[NN];   // 48 KB  (SoA, cell-sorted)
    __shared__ unsigned short sidx[NN];        // 8 KB   (local vertex idx)
    __shared__ unsigned cnt[NCELL];            // 4 KB   (counts -> cursor)
    __shared__ unsigned sstart[NCELL + 1];     // 4 KB   (exclusive starts)
    __shared__ unsigned wsum[BLK / 64];

    const int tid = threadIdx.x;
    const int c   = blockIdx.x >> 7;           // 128 blocks per class

    // ---- Phase A: stage 8 points/thread into registers ----
    for (int i = tid; i < NCELL; i += BLK) cnt[i] = 0u;
    const float4* src4 = (const float4*)(verts + (size_t)c * NN * 3);
    float f[24];
    #pragma unroll
    for (int u = 0; u < 6; ++u) {
        const float4 v = src4[6 * tid + u];
        f[4 * u + 0] = v.x; f[4 * u + 1] = v.y;
        f[4 * u + 2] = v.z; f[4 * u + 3] = v.w;
    }
    float px[PPT], py[PPT], pz[PPT];
    #pragma unroll
    for (int u = 0; u < PPT; ++u) {
        px[u] = f[3 * u]; py[u] = f[3 * u + 1]; pz[u] = f[3 * u + 2];
    }
    __syncthreads();                           // cnt zeroed

    int cell[PPT];
    #pragma unroll
    for (int u = 0; u < PPT; ++u) {
        cell[u] = (cellof(px[u]) * GR + cellof(py[u])) * GR + cellof(pz[u]);
        atomicAdd(&cnt[cell[u]], 1u);
    }
    __syncthreads();

    // ---- Phase B: exclusive scan of 1000 counts (thread t owns 2 cells) ----
    const int lane = tid & 63, wid = tid >> 6;
    unsigned own0 = 0u, own1 = 0u;
    if (tid < NCELL / 2) { own0 = cnt[2 * tid]; own1 = cnt[2 * tid + 1]; }
    const unsigned pair = own0 + own1;
    unsigned incl = pair;
    #pragma unroll
    for (int off = 1; off < 64; off <<= 1) {
        unsigned v = __shfl_up(incl, off);
        if (lane >= off) incl += v;
    }
    if (lane == 63) wsum[wid] = incl;
    __syncthreads();                           // also fences cnt reads above
    unsigned wbase = 0;
    for (int w = 0; w < wid; ++w) wbase += wsum[w];
    if (tid < NCELL / 2) {
        const unsigned exclp = wbase + incl - pair;   // exclusive over pairs
        sstart[2 * tid]     = exclp;
        sstart[2 * tid + 1] = exclp + own0;
        cnt[2 * tid]        = exclp;                  // scatter cursors
        cnt[2 * tid + 1]    = exclp + own0;
    }
    if (tid == NCELL / 2 - 1) sstart[NCELL] = wbase + incl;   // == NN
    __syncthreads();

    // ---- Phase C: scatter points into cell-sorted SoA ----
    #pragma unroll
    for (int u = 0; u < PPT; ++u) {
        const unsigned pos = atomicAdd(&cnt[cell[u]], 1u);
        sx[pos] = px[u]; sy[pos] = py[u]; sz[pos] = pz[u];
        sidx[pos] = (unsigned short)(PPT * tid + u);
    }
    __syncthreads();

    // ---- Phase D: 32 queries, 16 lanes each, all from LDS ----
    const int g = tid >> 4;                    // group 0..31
    const int t = tid & (LPQ - 1);
    const int m = blockIdx.x * QPB + g;        // global query slot
    const float qx = nverts[3 * m + 0];
    const float qy = nverts[3 * m + 1];
    const float qz = nverts[3 * m + 2];

    const int cx = cellof(qx), cy = cellof(qy), cz = cellof(qz);
    const int offb = (c == 0) ? NN : (-c * NN);   // off-block 1.0 seed indices
    const float cs = 1.0f / (float)GR;

    // Two independent top-3 sets (slot-0 chain / slot-1 chain) -> 2x ILP on
    // the serial insert chain; merged once below. Identical seeds dedupe
    // under strict <.
    float d0 = 1.0f, d1 = 1.0f, d2 = 1.0f;
    int   i0 = offb, i1 = offb + 1, i2 = offb + 2;
    float e0 = 1.0f, e1 = 1.0f, e2 = 1.0f;
    int   k0 = offb, k1 = offb + 1, k2 = offb + 2;

    const int lz = max(cz - 1, 0), hz = min(cz + 1, GR - 1);

    // 9 z-column ranges from LDS starts (broadcast within group).
    unsigned aa[9], bb[9];
    #pragma unroll
    for (int j = 0; j < 9; ++j) {
        const int ppx = cx + j / 3 - 1, ppy = cy + j % 3 - 1;
        const bool ok = (ppx >= 0) & (ppx < GR) & (ppy >= 0) & (ppy < GR);
        const int rb = ok ? ((ppx * GR + ppy) * GR) : 0;
        const unsigned av = sstart[rb + lz];
        const unsigned bv = sstart[rb + hz + 1];
        aa[j] = av;
        bb[j] = ok ? bv : av;                  // empty if out of grid
    }

    // 2-deep predicated batch: lanes t and t+16 cover 32 pts/column.
    unsigned over = 0u;
    #pragma unroll
    for (int j = 0; j < 9; ++j) {
        const unsigned s0 = aa[j] + t, s1 = s0 + LPQ;
        const unsigned u0 = (s0 < bb[j]) ? s0 : 0u;
        const unsigned u1 = (s1 < bb[j]) ? s1 : 0u;
        const float x0 = sx[u0], y0 = sy[u0], z0 = sz[u0];
        const float x1 = sx[u1], y1 = sy[u1], z1 = sz[u1];
        const int j0 = sidx[u0], j1 = sidx[u1];
        float dx = x0 - qx, dy = y0 - qy, dz = z0 - qz;
        float dd = fmaf(dx, dx, fmaf(dy, dy, dz * dz));
        dd = (s0 < bb[j]) ? dd : 1e30f;
        ins3b(dd, j0, d0, d1, d2, i0, i1, i2);
        dx = x1 - qx; dy = y1 - qy; dz = z1 - qz;
        float de = fmaf(dx, dx, fmaf(dy, dy, dz * dz));
        de = (s1 < bb[j]) ? de : 1e30f;
        ins3b(de, j1, e0, e1, e2, k0, k1, k2);
        over |= (bb[j] - aa[j] > 2u * LPQ) ? 1u : 0u;
    }
    // Merge slot-1 set into slot-0 set.
    ins3b(e0, k0, d0, d1, d2, i0, i1, i2);
    ins3b(e1, k1, d0, d1, d2, i0, i1, i2);
    ins3b(e2, k2, d0, d1, d2, i0, i1, i2);

    if (over) {                                // rare: columns > 32 pts
        #pragma unroll 1
        for (int j = 0; j < 9; ++j) {
            for (unsigned s = aa[j] + 2u * LPQ + t; s < bb[j]; s += LPQ) {
                const float dx = sx[s] - qx, dy = sy[s] - qy, dz = sz[s] - qz;
                const float dd = fmaf(dx, dx, fmaf(dy, dy, dz * dz));
                ins3b(dd, (int)sidx[s], d0, d1, d2, i0, i1, i2);
            }
        }
    }

    // Merge sorted triples across the 16-lane group.
    #pragma unroll
    for (int mask = 1; mask < LPQ; mask <<= 1) {
        const float m0 = __shfl_xor(d0, mask);
        const float m1 = __shfl_xor(d1, mask);
        const float m2 = __shfl_xor(d2, mask);
        const int   j0 = __shfl_xor(i0, mask);
        const int   j1 = __shfl_xor(i1, mask);
        const int   j2 = __shfl_xor(i2, mask);
        ins3b(m0, j0, d0, d1, d2, i0, i1, i2);
        ins3b(m1, j1, d0, d1, d2, i0, i1, i2);
        ins3b(m2, j2, d0, d1, d2, i0, i1, i2);
    }

    // Certificate for r=1 (group-uniform); rare exact expanding rescan.
    {
        const int lx = max(cx - 1, 0), hx = min(cx + 1, GR - 1);
        const int ly = max(cy - 1, 0), hy = min(cy + 1, GR - 1);
        float rmin = 1e30f;
        if (lx > 0)      rmin = fminf(rmin, qx - (float)lx * cs);
        if (hx < GR - 1) rmin = fminf(rmin, (float)(hx + 1) * cs - qx);
        if (ly > 0)      rmin = fminf(rmin, qy - (float)ly * cs);
        if (hy < GR - 1) rmin = fminf(rmin, (float)(hy + 1) * cs - qy);
        if (lz > 0)      rmin = fminf(rmin, qz - (float)lz * cs);
        if (hz < GR - 1) rmin = fminf(rmin, (float)(hz + 1) * cs - qz);

        if (!(d2 <= rmin * rmin)) {            // P ~ 5.8e-6 per query
            for (int r = 2;; ++r) {
                d0 = d1 = d2 = 1.0f;
                i0 = offb; i1 = offb + 1; i2 = offb + 2;
                const int Lx = max(cx - r, 0), Hx = min(cx + r, GR - 1);
                const int Ly = max(cy - r, 0), Hy = min(cy + r, GR - 1);
                const int Lz = max(cz - r, 0), Hz = min(cz + r, GR - 1);
                for (int ppx = Lx; ppx <= Hx; ++ppx) {
                    for (int ppy = Ly; ppy <= Hy; ++ppy) {
                        const int rb = (ppx * GR + ppy) * GR;
                        const unsigned a = sstart[rb + Lz];
                        const unsigned b = sstart[rb + Hz + 1];
                        for (unsigned s = a + t; s < b; s += LPQ) {
                            const float dx = sx[s] - qx, dy = sy[s] - qy,
                                        dz = sz[s] - qz;
                            const float dd =
                                fmaf(dx, dx, fmaf(dy, dy, dz * dz));
                            ins3b(dd, (int)sidx[s], d0, d1, d2, i0, i1, i2);
                        }
                    }
                }
                #pragma unroll
                for (int mask = 1; mask < LPQ; mask <<= 1) {
                    const float m0 = __shfl_xor(d0, mask);
                    const float m1 = __shfl_xor(d1, mask);
                    const float m2 = __shfl_xor(d2, mask);
                    const int   j0 = __shfl_xor(i0, mask);
                    const int   j1 = __shfl_xor(i1, mask);
                    const int   j2 = __shfl_xor(i2, mask);
                    ins3b(m0, j0, d0, d1, d2, i0, i1, i2);
                    ins3b(m1, j1, d0, d1, d2, i0, i1, i2);
                    ins3b(m2, j2, d0, d1, d2, i0, i1, i2);
                }
                float rm = 1e30f;
                if (Lx > 0)      rm = fminf(rm, qx - (float)Lx * cs);
                if (Hx < GR - 1) rm = fminf(rm, (float)(Hx + 1) * cs - qx);
                if (Ly > 0)      rm = fminf(rm, qy - (float)Ly * cs);
                if (Hy < GR - 1) rm = fminf(rm, (float)(Hy + 1) * cs - qy);
                if (Lz > 0)      rm = fminf(rm, qz - (float)Lz * cs);
                if (Hz < GR - 1) rm = fminf(rm, (float)(Hz + 1) * cs - qz);
                const bool full = (Lx == 0 && Ly == 0 && Lz == 0 &&
                                   Hx == GR - 1 && Hy == GR - 1 &&
                                   Hz == GR - 1);
                if (full || d2 <= rm * rm) break;
            }
        }
    }

    // Fused epilogue: softmax(-d) + weighted feature gather (float2/lane).
    float w1 = expf(d0 - d1);
    float w2 = expf(d0 - d2);
    const float inv = 1.0f / (1.0f + w1 + w2);
    const float w0 = inv;
    w1 *= inv; w2 *= inv;

    const float2 a  = feat2[(size_t)(i0 + c * NN) * 16 + t];
    const float2 b  = feat2[(size_t)(i1 + c * NN) * 16 + t];
    const float2 gg = feat2[(size_t)(i2 + c * NN) * 16 + t];
    float2 o;
    o.x = w0 * a.x + w1 * b.x + w2 * gg.x;
    o.y = w0 * a.y + w1 * b.y + w2 * gg.y;
    out2[(size_t)m * 16 + t] = o;              // natural order -> coalesced
}

extern "C" void kernel_launch(void* const* d_in, const int* in_sizes, int n_in,
                              void* d_out, int out_size, void* d_ws, size_t ws_size,
                              hipStream_t stream) {
    const float* feat   = (const float*)d_in[0];   // points_feat [1, C*N, D] f32
    const float* verts  = (const float*)d_in[1];   // vertices    [C, N, 3]  f32
    const float* nverts = (const float*)d_in[2];   // new_vertices[C, M, 3]  f32
    float* outp = (float*)d_out;                   // [1, C*M, D] f32

    k_all<<<dim3(CC * MM / QPB), dim3(BLK), 0, stream>>>(
        (const float2*)feat, verts, nverts, (float2*)outp);
}

// Round 3
// 66.499 us; speedup vs baseline: 1.0815x; 1.0155x over previous
//
#include <hip/hip_runtime.h>
#include <math.h>

// Problem constants (fixed by setup_inputs).
#define CC 4
#define NN 4096                  // vertices per class (== queries per class)
#define MM 4096
#define DD 32
#define GR 10                    // grid resolution per axis
#define NCELL (GR * GR * GR)     // 1000 cells per class
#define LPQ 16                   // lanes cooperating per query
#define BLK 512                  // threads per block (8 waves -> 2 blocks/CU)
#define QPB 32                   // queries per block
#define PPT 8                    // points staged per thread (NN/BLK)

__device__ __forceinline__ int cellof(float x) {
    int c = (int)(x * (float)GR);
    return min(max(c, 0), GR - 1);
}

// Branchless sorted-insert of (d, j) into top-3 (d0<=d1<=d2). Strict <
// keeps earlier entries on ties (matches jax top_k tie-break).
__device__ __forceinline__ void ins3b(float d, int j,
                                      float& d0, float& d1, float& d2,
                                      int& i0, int& i1, int& i2) {
    bool l2 = d < d2, l1 = d < d1, l0 = d < d0;
    d2 = l1 ? d1 : (l2 ? d : d2);
    i2 = l1 ? i1 : (l2 ? j : i2);
    d1 = l0 ? d0 : (l1 ? d : d1);
    i1 = l0 ? i0 : (l1 ? j : i1);
    d0 = l0 ? d : d0;
    i0 = l0 ? j : i0;
}

// ONE fused kernel. Each block privately builds the full cell index of its
// class in LDS (count -> scan -> scatter into packed float4), then answers
// 32 queries with 16 lanes each via a COMPACT work-list sweep (every real
// point visited exactly once; no predicated waste, no scratch arrays).
__global__ __launch_bounds__(BLK, 4) void k_all(
    const float2* __restrict__ feat2,     // [CC*NN][16] float2
    const float* __restrict__ verts,      // [CC,NN,3]
    const float* __restrict__ nverts,     // [CC,MM,3]
    float2* __restrict__ out2)            // [CC*MM][16] float2
{
    __shared__ float4 s4[NN];                  // 64 KB {x,y,z,bitcast(idx)}
    __shared__ unsigned cnt[NCELL];            // 4 KB  (counts -> cursor)
    __shared__ unsigned sstart[NCELL + 1];     // 4 KB  (exclusive starts)
    __shared__ unsigned wsum[BLK / 64];

    const int tid = threadIdx.x;
    const int c   = blockIdx.x >> 7;           // 128 blocks per class

    // ---- Phase A: stage 8 points/thread into registers ----
    for (int i = tid; i < NCELL; i += BLK) cnt[i] = 0u;
    const float4* src4 = (const float4*)(verts + (size_t)c * NN * 3);
    float f[24];
    #pragma unroll
    for (int u = 0; u < 6; ++u) {
        const float4 v = src4[6 * tid + u];
        f[4 * u + 0] = v.x; f[4 * u + 1] = v.y;
        f[4 * u + 2] = v.z; f[4 * u + 3] = v.w;
    }
    float px[PPT], py[PPT], pz[PPT];
    #pragma unroll
    for (int u = 0; u < PPT; ++u) {
        px[u] = f[3 * u]; py[u] = f[3 * u + 1]; pz[u] = f[3 * u + 2];
    }
    __syncthreads();                           // cnt zeroed

    int cell[PPT];
    #pragma unroll
    for (int u = 0; u < PPT; ++u) {
        cell[u] = (cellof(px[u]) * GR + cellof(py[u])) * GR + cellof(pz[u]);
        atomicAdd(&cnt[cell[u]], 1u);
    }
    __syncthreads();

    // ---- Phase B: exclusive scan of 1000 counts (thread t owns 2 cells) ----
    const int lane = tid & 63, wid = tid >> 6;
    unsigned own0 = 0u, own1 = 0u;
    if (tid < NCELL / 2) { own0 = cnt[2 * tid]; own1 = cnt[2 * tid + 1]; }
    const unsigned pair = own0 + own1;
    unsigned incl = pair;
    #pragma unroll
    for (int off = 1; off < 64; off <<= 1) {
        unsigned v = __shfl_up(incl, off);
        if (lane >= off) incl += v;
    }
    if (lane == 63) wsum[wid] = incl;
    __syncthreads();                           // also fences cnt reads above
    unsigned wbase = 0;
    for (int w = 0; w < wid; ++w) wbase += wsum[w];
    if (tid < NCELL / 2) {
        const unsigned exclp = wbase + incl - pair;   // exclusive over pairs
        sstart[2 * tid]     = exclp;
        sstart[2 * tid + 1] = exclp + own0;
        cnt[2 * tid]        = exclp;                  // scatter cursors
        cnt[2 * tid + 1]    = exclp + own0;
    }
    if (tid == NCELL / 2 - 1) sstart[NCELL] = wbase + incl;   // == NN
    __syncthreads();

    // ---- Phase C: scatter points into cell-sorted packed float4 ----
    #pragma unroll
    for (int u = 0; u < PPT; ++u) {
        const unsigned pos = atomicAdd(&cnt[cell[u]], 1u);
        s4[pos] = make_float4(px[u], py[u], pz[u],
                              __int_as_float(PPT * tid + u));
    }
    __syncthreads();

    // ---- Phase D: 32 queries, 16 lanes each, compact sweep from LDS ----
    const int g = tid >> 4;                    // group 0..31
    const int t = tid & (LPQ - 1);
    const int m = blockIdx.x * QPB + g;        // global query slot
    const float qx = nverts[3 * m + 0];
    const float qy = nverts[3 * m + 1];
    const float qz = nverts[3 * m + 2];

    const int cx = cellof(qx), cy = cellof(qy), cz = cellof(qz);
    const int offb = (c == 0) ? NN : (-c * NN);   // off-block 1.0 seed indices
    const float cs = 1.0f / (float)GR;

    // Two independent top-3 sets for ILP on the serial insert chain;
    // merged once below. Identical seeds dedupe under strict <.
    float d0 = 1.0f, d1 = 1.0f, d2 = 1.0f;
    int   i0 = offb, i1 = offb + 1, i2 = offb + 2;
    float e0 = 1.0f, e1 = 1.0f, e2 = 1.0f;
    int   k0 = offb, k1 = offb + 1, k2 = offb + 2;

    const int lz = max(cz - 1, 0), hz = min(cz + 1, GR - 1);

    // Per-group compact work list over the 9 z-columns: cum[j] = first
    // work-slot of column j, shf[j] maps slot -> LDS index. All accesses
    // are fully unrolled / statically indexed -> stays in VGPRs.
    unsigned shf[9], cum[10];
    cum[0] = 0u;
    #pragma unroll
    for (int j = 0; j < 9; ++j) {
        const int ppx = cx + j / 3 - 1, ppy = cy + j % 3 - 1;
        const bool ok = (ppx >= 0) & (ppx < GR) & (ppy >= 0) & (ppy < GR);
        const int rb = ok ? ((ppx * GR + ppy) * GR) : 0;
        const unsigned av = sstart[rb + lz];
        const unsigned bv = ok ? sstart[rb + hz + 1] : av;
        shf[j] = av - cum[j];                  // unsigned wrap is fine
        cum[j + 1] = cum[j] + (bv - av);
    }
    const unsigned L = cum[9];                 // ~110 real candidates

    // Sweep: 2 candidates/iter (lanes t and t+16 of the work list).
    for (unsigned s = t; s < L; s += 2u * LPQ) {
        const unsigned sB = s + LPQ;
        unsigned shA = shf[0], shB = shf[0];
        #pragma unroll
        for (int k = 1; k < 9; ++k) {
            shA = (s  >= cum[k]) ? shf[k] : shA;
            shB = (sB >= cum[k]) ? shf[k] : shB;
        }
        const float4 pA = s4[s + shA];
        const unsigned uB = (sB < L) ? (sB + shB) : (s + shA);
        const float4 pB = s4[uB];
        float dx = pA.x - qx, dy = pA.y - qy, dz = pA.z - qz;
        const float dA = fmaf(dx, dx, fmaf(dy, dy, dz * dz));
        ins3b(dA, __float_as_int(pA.w), d0, d1, d2, i0, i1, i2);
        dx = pB.x - qx; dy = pB.y - qy; dz = pB.z - qz;
        float dB = fmaf(dx, dx, fmaf(dy, dy, dz * dz));
        dB = (sB < L) ? dB : 1e30f;
        ins3b(dB, __float_as_int(pB.w), e0, e1, e2, k0, k1, k2);
    }
    // Merge slot-1 set into slot-0 set.
    ins3b(e0, k0, d0, d1, d2, i0, i1, i2);
    ins3b(e1, k1, d0, d1, d2, i0, i1, i2);
    ins3b(e2, k2, d0, d1, d2, i0, i1, i2);

    // Merge sorted triples across the 16-lane group.
    #pragma unroll
    for (int mask = 1; mask < LPQ; mask <<= 1) {
        const float m0 = __shfl_xor(d0, mask);
        const float m1 = __shfl_xor(d1, mask);
        const float m2 = __shfl_xor(d2, mask);
        const int   j0 = __shfl_xor(i0, mask);
        const int   j1 = __shfl_xor(i1, mask);
        const int   j2 = __shfl_xor(i2, mask);
        ins3b(m0, j0, d0, d1, d2, i0, i1, i2);
        ins3b(m1, j1, d0, d1, d2, i0, i1, i2);
        ins3b(m2, j2, d0, d1, d2, i0, i1, i2);
    }

    // Certificate for r=1 (group-uniform); rare exact expanding rescan.
    {
        const int lx = max(cx - 1, 0), hx = min(cx + 1, GR - 1);
        const int ly = max(cy - 1, 0), hy = min(cy + 1, GR - 1);
        float rmin = 1e30f;
        if (lx > 0)      rmin = fminf(rmin, qx - (float)lx * cs);
        if (hx < GR - 1) rmin = fminf(rmin, (float)(hx + 1) * cs - qx);
        if (ly > 0)      rmin = fminf(rmin, qy - (float)ly * cs);
        if (hy < GR - 1) rmin = fminf(rmin, (float)(hy + 1) * cs - qy);
        if (lz > 0)      rmin = fminf(rmin, qz - (float)lz * cs);
        if (hz < GR - 1) rmin = fminf(rmin, (float)(hz + 1) * cs - qz);

        if (!(d2 <= rmin * rmin)) {            // P ~ 5.8e-6 per query
            for (int r = 2;; ++r) {
                d0 = d1 = d2 = 1.0f;
                i0 = offb; i1 = offb + 1; i2 = offb + 2;
                const int Lx = max(cx - r, 0), Hx = min(cx + r, GR - 1);
                const int Ly = max(cy - r, 0), Hy = min(cy + r, GR - 1);
                const int Lz = max(cz - r, 0), Hz = min(cz + r, GR - 1);
                for (int ppx = Lx; ppx <= Hx; ++ppx) {
                    for (int ppy = Ly; ppy <= Hy; ++ppy) {
                        const int rb = (ppx * GR + ppy) * GR;
                        const unsigned a = sstart[rb + Lz];
                        const unsigned b = sstart[rb + Hz + 1];
                        for (unsigned s = a + t; s < b; s += LPQ) {
                            const float4 p = s4[s];
                            const float dx = p.x - qx, dy = p.y - qy,
                                        dz = p.z - qz;
                            const float dd =
                                fmaf(dx, dx, fmaf(dy, dy, dz * dz));
                            ins3b(dd, __float_as_int(p.w),
                                  d0, d1, d2, i0, i1, i2);
                        }
                    }
                }
                #pragma unroll
                for (int mask = 1; mask < LPQ; mask <<= 1) {
                    const float m0 = __shfl_xor(d0, mask);
                    const float m1 = __shfl_xor(d1, mask);
                    const float m2 = __shfl_xor(d2, mask);
                    const int   j0 = __shfl_xor(i0, mask);
                    const int   j1 = __shfl_xor(i1, mask);
                    const int   j2 = __shfl_xor(i2, mask);
                    ins3b(m0, j0, d0, d1, d2, i0, i1, i2);
                    ins3b(m1, j1, d0, d1, d2, i0, i1, i2);
                    ins3b(m2, j2, d0, d1, d2, i0, i1, i2);
                }
                float rm = 1e30f;
                if (Lx > 0)      rm = fminf(rm, qx - (float)Lx * cs);
                if (Hx < GR - 1) rm = fminf(rm, (float)(Hx + 1) * cs - qx);
                if (Ly > 0)      rm = fminf(rm, qy - (float)Ly * cs);
                if (Hy < GR - 1) rm = fminf(rm, (float)(Hy + 1) * cs - qy);
                if (Lz > 0)      rm = fminf(rm, qz - (float)Lz * cs);
                if (Hz < GR - 1) rm = fminf(rm, (float)(Hz + 1) * cs - qz);
                const bool full = (Lx == 0 && Ly == 0 && Lz == 0 &&
                                   Hx == GR - 1 && Hy == GR - 1 &&
                                   Hz == GR - 1);
                if (full || d2 <= rm * rm) break;
            }
        }
    }

    // Fused epilogue: softmax(-d) + weighted feature gather (float2/lane).
    float w1 = expf(d0 - d1);
    float w2 = expf(d0 - d2);
    const float inv = 1.0f / (1.0f + w1 + w2);
    const float w0 = inv;
    w1 *= inv; w2 *= inv;

    const float2 a  = feat2[(size_t)(i0 + c * NN) * 16 + t];
    const float2 b  = feat2[(size_t)(i1 + c * NN) * 16 + t];
    const float2 gg = feat2[(size_t)(i2 + c * NN) * 16 + t];
    float2 o;
    o.x = w0 * a.x + w1 * b.x + w2 * gg.x;
    o.y = w0 * a.y + w1 * b.y + w2 * gg.y;
    out2[(size_t)m * 16 + t] = o;              // natural order -> coalesced
}

extern "C" void kernel_launch(void* const* d_in, const int* in_sizes, int n_in,
                              void* d_out, int out_size, void* d_ws, size_t ws_size,
                              hipStream_t stream) {
    const float* feat   = (const float*)d_in[0];   // points_feat [1, C*N, D] f32
    const float* verts  = (const float*)d_in[1];   // vertices    [C, N, 3]  f32
    const float* nverts = (const float*)d_in[2];   // new_vertices[C, M, 3]  f32
    float* outp = (float*)d_out;                   // [1, C*M, D] f32

    k_all<<<dim3(CC * MM / QPB), dim3(BLK), 0, stream>>>(
        (const float2*)feat, verts, nverts, (float2*)outp);
}